// Round 1
// baseline (3151.337 us; speedup 1.0000x reference)
//
#include <hip/hip_runtime.h>
#include <math.h>

// MoE FFN: top-2 of 8 experts + shared expert, H=1024, F=2048, N=4096.
// Round 1: correct fp32 implementation, sparse (top-2 only) routed compute.
// Structure: router -> bucket by expert -> grouped GEMMs -> combine.

#define H_DIM 1024
#define F_DIM 2048
#define E_NUM 8
#define EPSV 1e-9f

// ---------------- router ----------------
// 1 wave per token: logits (8 dots of len 1024), softmax, top-2, z.
// Scatters (token) into per-expert buckets with atomic counters, and
// accumulates aux-loss reductions (importance, load, sum z^2).
__global__ void moe_router_kernel(const float* __restrict__ X,
                                  const float* __restrict__ Wr, int N,
                                  int* __restrict__ count, float* __restrict__ imp,
                                  float* __restrict__ loadc, float* __restrict__ zsq,
                                  int* __restrict__ idxA, int* __restrict__ posA,
                                  float* __restrict__ wA, int* __restrict__ bucket_tok)
{
    int wave = threadIdx.x >> 6;
    int lane = threadIdx.x & 63;
    int n = blockIdx.x * 4 + wave;

    __shared__ float s_p[4][8];
    __shared__ float s_zz[4];
    __shared__ int   s_t1[4];

    float acc[8];
#pragma unroll
    for (int e = 0; e < 8; e++) acc[e] = 0.f;
    const float* xr = X + (size_t)n * H_DIM;
    for (int h = lane; h < H_DIM; h += 64) {
        float xv = xr[h];
#pragma unroll
        for (int e = 0; e < 8; e++) acc[e] += xv * Wr[e * H_DIM + h];
    }
#pragma unroll
    for (int off = 32; off > 0; off >>= 1) {
#pragma unroll
        for (int e = 0; e < 8; e++) acc[e] += __shfl_xor(acc[e], off, 64);
    }

    if (lane == 0) {
        float m = acc[0];
#pragma unroll
        for (int e = 1; e < 8; e++) m = fmaxf(m, acc[e]);
        float p[8];
        float s = 0.f;
#pragma unroll
        for (int e = 0; e < 8; e++) { p[e] = expf(acc[e] - m); s += p[e]; }
        float z = m + logf(s);
        float inv = 1.f / s;
#pragma unroll
        for (int e = 0; e < 8; e++) p[e] *= inv;
        // top-1 then top-2, strict > keeps lowest index on ties (matches lax.top_k)
        int t1 = 0; float b1 = p[0];
#pragma unroll
        for (int e = 1; e < 8; e++) if (p[e] > b1) { b1 = p[e]; t1 = e; }
        int t2 = (t1 == 0) ? 1 : 0; float b2 = p[t2];
#pragma unroll
        for (int e = 0; e < 8; e++) if (e != t1 && p[e] > b2) { b2 = p[e]; t2 = e; }

        float wsum = b1 + b2 + EPSV;
        float w0 = b1 / wsum, w1 = b2 / wsum;

        int pos0 = atomicAdd(&count[t1], 1);
        int pos1 = atomicAdd(&count[t2], 1);
        bucket_tok[t1 * N + pos0] = n;
        bucket_tok[t2 * N + pos1] = n;
        idxA[2 * n] = t1; idxA[2 * n + 1] = t2;
        posA[2 * n] = pos0; posA[2 * n + 1] = pos1;
        wA[2 * n] = w0; wA[2 * n + 1] = w1;

#pragma unroll
        for (int e = 0; e < 8; e++) s_p[wave][e] = p[e];
        s_zz[wave] = z * z;
        s_t1[wave] = t1;
    }
    __syncthreads();
    if (threadIdx.x < 8) {
        int e = threadIdx.x;
        atomicAdd(&imp[e], s_p[0][e] + s_p[1][e] + s_p[2][e] + s_p[3][e]);
        float cl = 0.f;
#pragma unroll
        for (int w = 0; w < 4; w++) cl += (s_t1[w] == e) ? 1.f : 0.f;
        if (cl > 0.f) atomicAdd(&loadc[e], cl);
    } else if (threadIdx.x == 8) {
        atomicAdd(zsq, s_zz[0] + s_zz[1] + s_zz[2] + s_zz[3]);
    }
}

__global__ void moe_offsets_kernel(const int* __restrict__ count, int* __restrict__ offsets)
{
    int o = 0;
    for (int e = 0; e < E_NUM; e++) { offsets[e] = o; o += count[e]; }
}

// ---------------- shared expert: gate+up fused ----------------
// Hsh[n][f] = silu(x@Wg^T) * (x@Wu^T); 64x64 tile, BK=32, 4x4 per thread.
__global__ void __launch_bounds__(256)
moe_sh_gateup_kernel(const float* __restrict__ X, const float* __restrict__ Wg,
                     const float* __restrict__ Wu, float* __restrict__ Hsh)
{
    __shared__ float As[64][33];
    __shared__ float Bg[64][33];
    __shared__ float Bu[64][33];
    int f0 = blockIdx.x * 64;
    int m0 = blockIdx.y * 64;
    int t = threadIdx.x;
    int tx = t & 15, ty = t >> 4;
    int lr = t >> 3;
    int lc = (t & 7) * 4;
    float accg[4][4] = {{0}}, accu[4][4] = {{0}};

    for (int k0 = 0; k0 < H_DIM; k0 += 32) {
#pragma unroll
        for (int p = 0; p < 2; p++) {
            int r = lr + p * 32;
            float4 va = *(const float4*)&X[(size_t)(m0 + r) * H_DIM + k0 + lc];
            As[r][lc + 0] = va.x; As[r][lc + 1] = va.y; As[r][lc + 2] = va.z; As[r][lc + 3] = va.w;
            float4 vg = *(const float4*)&Wg[(size_t)(f0 + r) * H_DIM + k0 + lc];
            Bg[r][lc + 0] = vg.x; Bg[r][lc + 1] = vg.y; Bg[r][lc + 2] = vg.z; Bg[r][lc + 3] = vg.w;
            float4 vu = *(const float4*)&Wu[(size_t)(f0 + r) * H_DIM + k0 + lc];
            Bu[r][lc + 0] = vu.x; Bu[r][lc + 1] = vu.y; Bu[r][lc + 2] = vu.z; Bu[r][lc + 3] = vu.w;
        }
        __syncthreads();
#pragma unroll
        for (int kk = 0; kk < 32; kk++) {
            float a[4], bg[4], bu[4];
#pragma unroll
            for (int i = 0; i < 4; i++) a[i] = As[ty * 4 + i][kk];
#pragma unroll
            for (int j = 0; j < 4; j++) { bg[j] = Bg[tx * 4 + j][kk]; bu[j] = Bu[tx * 4 + j][kk]; }
#pragma unroll
            for (int i = 0; i < 4; i++)
#pragma unroll
                for (int j = 0; j < 4; j++) {
                    accg[i][j] += a[i] * bg[j];
                    accu[i][j] += a[i] * bu[j];
                }
        }
        __syncthreads();
    }
#pragma unroll
    for (int i = 0; i < 4; i++)
#pragma unroll
        for (int j = 0; j < 4; j++) {
            float g = accg[i][j];
            float hv = g / (1.f + expf(-g)) * accu[i][j];
            Hsh[(size_t)(m0 + ty * 4 + i) * F_DIM + f0 + tx * 4 + j] = hv;
        }
}

// ---------------- routed experts: gate+up fused (gathered rows) ----------------
__global__ void __launch_bounds__(256)
moe_ex_gateup_kernel(const float* __restrict__ X, const float* __restrict__ Wg_all,
                     const float* __restrict__ Wu_all, const int* __restrict__ count,
                     const int* __restrict__ offsets, const int* __restrict__ bucket_tok,
                     float* __restrict__ He, int N)
{
    int e = blockIdx.z;
    int cnt = count[e];
    int m0 = blockIdx.y * 64;
    if (m0 >= cnt) return;
    int f0 = blockIdx.x * 64;
    int base = offsets[e];
    const float* Wg = Wg_all + (size_t)e * F_DIM * H_DIM;
    const float* Wu = Wu_all + (size_t)e * F_DIM * H_DIM;

    __shared__ int rows[64];
    __shared__ float As[64][33];
    __shared__ float Bg[64][33];
    __shared__ float Bu[64][33];
    if (threadIdx.x < 64) {
        int r = m0 + threadIdx.x;
        rows[threadIdx.x] = bucket_tok[(size_t)e * N + ((r < cnt) ? r : (cnt - 1))];
    }
    __syncthreads();

    int t = threadIdx.x;
    int tx = t & 15, ty = t >> 4;
    int lr = t >> 3;
    int lc = (t & 7) * 4;
    float accg[4][4] = {{0}}, accu[4][4] = {{0}};

    for (int k0 = 0; k0 < H_DIM; k0 += 32) {
#pragma unroll
        for (int p = 0; p < 2; p++) {
            int r = lr + p * 32;
            float4 va = *(const float4*)&X[(size_t)rows[r] * H_DIM + k0 + lc];
            As[r][lc + 0] = va.x; As[r][lc + 1] = va.y; As[r][lc + 2] = va.z; As[r][lc + 3] = va.w;
            float4 vg = *(const float4*)&Wg[(size_t)(f0 + r) * H_DIM + k0 + lc];
            Bg[r][lc + 0] = vg.x; Bg[r][lc + 1] = vg.y; Bg[r][lc + 2] = vg.z; Bg[r][lc + 3] = vg.w;
            float4 vu = *(const float4*)&Wu[(size_t)(f0 + r) * H_DIM + k0 + lc];
            Bu[r][lc + 0] = vu.x; Bu[r][lc + 1] = vu.y; Bu[r][lc + 2] = vu.z; Bu[r][lc + 3] = vu.w;
        }
        __syncthreads();
#pragma unroll
        for (int kk = 0; kk < 32; kk++) {
            float a[4], bg[4], bu[4];
#pragma unroll
            for (int i = 0; i < 4; i++) a[i] = As[ty * 4 + i][kk];
#pragma unroll
            for (int j = 0; j < 4; j++) { bg[j] = Bg[tx * 4 + j][kk]; bu[j] = Bu[tx * 4 + j][kk]; }
#pragma unroll
            for (int i = 0; i < 4; i++)
#pragma unroll
                for (int j = 0; j < 4; j++) {
                    accg[i][j] += a[i] * bg[j];
                    accu[i][j] += a[i] * bu[j];
                }
        }
        __syncthreads();
    }
#pragma unroll
    for (int i = 0; i < 4; i++) {
        int r = ty * 4 + i;
        if (m0 + r < cnt) {
#pragma unroll
            for (int j = 0; j < 4; j++) {
                float g = accg[i][j];
                float hv = g / (1.f + expf(-g)) * accu[i][j];
                He[(size_t)(base + m0 + r) * F_DIM + f0 + tx * 4 + j] = hv;
            }
        }
    }
}

// ---------------- routed experts: down proj -> R (unweighted) ----------------
__global__ void __launch_bounds__(256)
moe_ex_down_kernel(const float* __restrict__ He, const float* __restrict__ Wd_all,
                   const int* __restrict__ count, const int* __restrict__ offsets,
                   float* __restrict__ R)
{
    int e = blockIdx.z;
    int cnt = count[e];
    int m0 = blockIdx.y * 64;
    if (m0 >= cnt) return;
    int h0 = blockIdx.x * 64;
    int base = offsets[e];
    const float* Wd = Wd_all + (size_t)e * H_DIM * F_DIM;

    __shared__ float As[64][33];
    __shared__ float Bs[64][33];
    int t = threadIdx.x;
    int tx = t & 15, ty = t >> 4;
    int lr = t >> 3;
    int lc = (t & 7) * 4;
    float acc[4][4] = {{0}};

    for (int k0 = 0; k0 < F_DIM; k0 += 32) {
#pragma unroll
        for (int p = 0; p < 2; p++) {
            int r = lr + p * 32;
            int rr = m0 + r; if (rr >= cnt) rr = cnt - 1;
            float4 va = *(const float4*)&He[(size_t)(base + rr) * F_DIM + k0 + lc];
            As[r][lc + 0] = va.x; As[r][lc + 1] = va.y; As[r][lc + 2] = va.z; As[r][lc + 3] = va.w;
            float4 vb = *(const float4*)&Wd[(size_t)(h0 + r) * F_DIM + k0 + lc];
            Bs[r][lc + 0] = vb.x; Bs[r][lc + 1] = vb.y; Bs[r][lc + 2] = vb.z; Bs[r][lc + 3] = vb.w;
        }
        __syncthreads();
#pragma unroll
        for (int kk = 0; kk < 32; kk++) {
            float a[4], b[4];
#pragma unroll
            for (int i = 0; i < 4; i++) a[i] = As[ty * 4 + i][kk];
#pragma unroll
            for (int j = 0; j < 4; j++) b[j] = Bs[tx * 4 + j][kk];
#pragma unroll
            for (int i = 0; i < 4; i++)
#pragma unroll
                for (int j = 0; j < 4; j++) acc[i][j] += a[i] * b[j];
        }
        __syncthreads();
    }
#pragma unroll
    for (int i = 0; i < 4; i++) {
        int r = ty * 4 + i;
        if (m0 + r < cnt) {
#pragma unroll
            for (int j = 0; j < 4; j++)
                R[(size_t)(base + m0 + r) * H_DIM + h0 + tx * 4 + j] = acc[i][j];
        }
    }
}

// ---------------- shared down + top-2 combine ----------------
__global__ void __launch_bounds__(256)
moe_sh_down_combine_kernel(const float* __restrict__ Hsh, const float* __restrict__ Wd,
                           const float* __restrict__ R, const int* __restrict__ idxA,
                           const int* __restrict__ posA, const float* __restrict__ wA,
                           const int* __restrict__ offsets, float* __restrict__ Y)
{
    int h0 = blockIdx.x * 64;
    int m0 = blockIdx.y * 64;

    __shared__ float As[64][33];
    __shared__ float Bs[64][33];
    __shared__ int r0s[64], r1s[64];
    __shared__ float w0s[64], w1s[64];
    if (threadIdx.x < 64) {
        int n = m0 + threadIdx.x;
        int e0 = idxA[2 * n], e1 = idxA[2 * n + 1];
        r0s[threadIdx.x] = offsets[e0] + posA[2 * n];
        r1s[threadIdx.x] = offsets[e1] + posA[2 * n + 1];
        w0s[threadIdx.x] = wA[2 * n];
        w1s[threadIdx.x] = wA[2 * n + 1];
    }

    int t = threadIdx.x;
    int tx = t & 15, ty = t >> 4;
    int lr = t >> 3;
    int lc = (t & 7) * 4;
    float acc[4][4] = {{0}};

    for (int k0 = 0; k0 < F_DIM; k0 += 32) {
#pragma unroll
        for (int p = 0; p < 2; p++) {
            int r = lr + p * 32;
            float4 va = *(const float4*)&Hsh[(size_t)(m0 + r) * F_DIM + k0 + lc];
            As[r][lc + 0] = va.x; As[r][lc + 1] = va.y; As[r][lc + 2] = va.z; As[r][lc + 3] = va.w;
            float4 vb = *(const float4*)&Wd[(size_t)(h0 + r) * F_DIM + k0 + lc];
            Bs[r][lc + 0] = vb.x; Bs[r][lc + 1] = vb.y; Bs[r][lc + 2] = vb.z; Bs[r][lc + 3] = vb.w;
        }
        __syncthreads();
#pragma unroll
        for (int kk = 0; kk < 32; kk++) {
            float a[4], b[4];
#pragma unroll
            for (int i = 0; i < 4; i++) a[i] = As[ty * 4 + i][kk];
#pragma unroll
            for (int j = 0; j < 4; j++) b[j] = Bs[tx * 4 + j][kk];
#pragma unroll
            for (int i = 0; i < 4; i++)
#pragma unroll
                for (int j = 0; j < 4; j++) acc[i][j] += a[i] * b[j];
        }
        __syncthreads();
    }
#pragma unroll
    for (int i = 0; i < 4; i++) {
        int r = ty * 4 + i;
        int n = m0 + r;
        const float* R0 = R + (size_t)r0s[r] * H_DIM;
        const float* R1 = R + (size_t)r1s[r] * H_DIM;
        float w0 = w0s[r], w1 = w1s[r];
#pragma unroll
        for (int j = 0; j < 4; j++) {
            int h = h0 + tx * 4 + j;
            Y[(size_t)n * H_DIM + h] = acc[i][j] + w0 * R0[h] + w1 * R1[h];
        }
    }
}

// ---------------- aux loss ----------------
__global__ void moe_aux_kernel(const float* __restrict__ imp, const float* __restrict__ loadc,
                               const float* __restrict__ zsq, float* __restrict__ out, int N)
{
    float is = 0.f, ls = 0.f;
    for (int e = 0; e < E_NUM; e++) { is += imp[e]; ls += loadc[e]; }
    float lb = 0.f;
    for (int e = 0; e < E_NUM; e++)
        lb += (imp[e] / (is + EPSV)) * (loadc[e] / (ls + EPSV));
    lb *= (float)E_NUM;
    float z_loss = 0.001f * (zsq[0] / (float)N);
    out[0] = 0.01f * lb + z_loss;
}

extern "C" void kernel_launch(void* const* d_in, const int* in_sizes, int n_in,
                              void* d_out, int out_size, void* d_ws, size_t ws_size,
                              hipStream_t stream)
{
    const float* x         = (const float*)d_in[0];
    const float* w_router  = (const float*)d_in[1];
    const float* w_sh_gate = (const float*)d_in[2];
    const float* w_sh_up   = (const float*)d_in[3];
    const float* w_sh_down = (const float*)d_in[4];
    const float* w_e_gate  = (const float*)d_in[5];
    const float* w_e_up    = (const float*)d_in[6];
    const float* w_e_down  = (const float*)d_in[7];
    float* out = (float*)d_out;
    int N = in_sizes[0] / H_DIM;  // 4096

    char* ws = (char*)d_ws;
    int*   count   = (int*)(ws + 0);
    int*   offsets = (int*)(ws + 32);
    float* imp     = (float*)(ws + 64);
    float* loadc   = (float*)(ws + 96);
    float* zsq     = (float*)(ws + 128);
    size_t off = 256;
    int*   idxA = (int*)(ws + off);  off += (size_t)N * 2 * 4;
    int*   posA = (int*)(ws + off);  off += (size_t)N * 2 * 4;
    float* wA   = (float*)(ws + off); off += (size_t)N * 2 * 4;
    int*   bucket_tok = (int*)(ws + off); off += (size_t)E_NUM * N * 4;
    off = (off + 255) & ~(size_t)255;
    float* Hsh = (float*)(ws + off); off += (size_t)N * F_DIM * 4;
    float* He  = (float*)(ws + off); off += (size_t)2 * N * F_DIM * 4;
    float* R   = (float*)(ws + off); off += (size_t)2 * N * H_DIM * 4;

    hipMemsetAsync(ws, 0, 256, stream);
    moe_router_kernel<<<N / 4, 256, 0, stream>>>(x, w_router, N, count, imp, loadc, zsq,
                                                 idxA, posA, wA, bucket_tok);
    moe_offsets_kernel<<<1, 1, 0, stream>>>(count, offsets);
    moe_ex_gateup_kernel<<<dim3(F_DIM / 64, N / 64, E_NUM), 256, 0, stream>>>(
        x, w_e_gate, w_e_up, count, offsets, bucket_tok, He, N);
    moe_ex_down_kernel<<<dim3(H_DIM / 64, N / 64, E_NUM), 256, 0, stream>>>(
        He, w_e_down, count, offsets, R);
    moe_sh_gateup_kernel<<<dim3(F_DIM / 64, N / 64), 256, 0, stream>>>(
        x, w_sh_gate, w_sh_up, Hsh);
    moe_sh_down_combine_kernel<<<dim3(H_DIM / 64, N / 64), 256, 0, stream>>>(
        Hsh, w_sh_down, R, idxA, posA, wA, offsets, out);
    moe_aux_kernel<<<1, 1, 0, stream>>>(imp, loadc, zsq, out + (size_t)N * H_DIM, N);
}

// Round 2
// 687.811 us; speedup vs baseline: 4.5817x; 4.5817x over previous
//
#include <hip/hip_runtime.h>
#include <math.h>

// MoE FFN: top-2 of 8 experts + shared expert, H=1024, F=2048, N=4096.
// Round 2: bf16 MFMA GEMMs (m97 structure: 128x128 tile, 16x16x32 MFMA,
// global_load_lds width=16). Router stays fp32 (top-k selection stability).

#define H_DIM 1024
#define F_DIM 2048
#define E_NUM 8
#define EPSV 1e-9f

typedef __bf16 bf16x8 __attribute__((ext_vector_type(8)));
typedef float f32x4 __attribute__((ext_vector_type(4)));

#define MFMA16(a, b, c) __builtin_amdgcn_mfma_f32_16x16x32_bf16(a, b, c, 0, 0, 0)

__device__ __forceinline__ unsigned f2bf(float f) {
    unsigned u = __float_as_uint(f);
    return (u + 0x7FFFu + ((u >> 16) & 1u)) >> 16;  // RNE
}

// async global->LDS, 16B per lane; lds ptr must be wave-uniform
__device__ __forceinline__ void gload16(const ushort* g, ushort* l) {
    __builtin_amdgcn_global_load_lds(
        (__attribute__((address_space(1))) void*)(void*)const_cast<ushort*>(g),
        (__attribute__((address_space(3))) void*)l, 16, 0, 0);
}

// ---------------- fp32 -> bf16 conversion (8 elems/thread) ----------------
__global__ void cvt_bf16_kernel(const float* __restrict__ src, ushort* __restrict__ dst, int n8) {
    int i = blockIdx.x * 256 + threadIdx.x;
    if (i >= n8) return;
    float4 a = ((const float4*)src)[2 * i];
    float4 b = ((const float4*)src)[2 * i + 1];
    uint4 o;
    o.x = f2bf(a.x) | (f2bf(a.y) << 16);
    o.y = f2bf(a.z) | (f2bf(a.w) << 16);
    o.z = f2bf(b.x) | (f2bf(b.y) << 16);
    o.w = f2bf(b.z) | (f2bf(b.w) << 16);
    ((uint4*)dst)[i] = o;
}

// ---------------- router (fp32, unchanged from R1) ----------------
__global__ void moe_router_kernel(const float* __restrict__ X,
                                  const float* __restrict__ Wr, int N,
                                  int* __restrict__ count, float* __restrict__ imp,
                                  float* __restrict__ loadc, float* __restrict__ zsq,
                                  int* __restrict__ idxA, int* __restrict__ posA,
                                  float* __restrict__ wA, int* __restrict__ bucket_tok)
{
    int wave = threadIdx.x >> 6;
    int lane = threadIdx.x & 63;
    int n = blockIdx.x * 4 + wave;

    __shared__ float s_p[4][8];
    __shared__ float s_zz[4];
    __shared__ int   s_t1[4];

    float acc[8];
#pragma unroll
    for (int e = 0; e < 8; e++) acc[e] = 0.f;
    const float* xr = X + (size_t)n * H_DIM;
    for (int h = lane; h < H_DIM; h += 64) {
        float xv = xr[h];
#pragma unroll
        for (int e = 0; e < 8; e++) acc[e] += xv * Wr[e * H_DIM + h];
    }
#pragma unroll
    for (int off = 32; off > 0; off >>= 1) {
#pragma unroll
        for (int e = 0; e < 8; e++) acc[e] += __shfl_xor(acc[e], off, 64);
    }

    if (lane == 0) {
        float m = acc[0];
#pragma unroll
        for (int e = 1; e < 8; e++) m = fmaxf(m, acc[e]);
        float p[8];
        float s = 0.f;
#pragma unroll
        for (int e = 0; e < 8; e++) { p[e] = expf(acc[e] - m); s += p[e]; }
        float z = m + logf(s);
        float inv = 1.f / s;
#pragma unroll
        for (int e = 0; e < 8; e++) p[e] *= inv;
        int t1 = 0; float b1 = p[0];
#pragma unroll
        for (int e = 1; e < 8; e++) if (p[e] > b1) { b1 = p[e]; t1 = e; }
        int t2 = (t1 == 0) ? 1 : 0; float b2 = p[t2];
#pragma unroll
        for (int e = 0; e < 8; e++) if (e != t1 && p[e] > b2) { b2 = p[e]; t2 = e; }

        float wsum = b1 + b2 + EPSV;
        float w0 = b1 / wsum, w1 = b2 / wsum;

        int pos0 = atomicAdd(&count[t1], 1);
        int pos1 = atomicAdd(&count[t2], 1);
        bucket_tok[t1 * N + pos0] = n;
        bucket_tok[t2 * N + pos1] = n;
        idxA[2 * n] = t1; idxA[2 * n + 1] = t2;
        posA[2 * n] = pos0; posA[2 * n + 1] = pos1;
        wA[2 * n] = w0; wA[2 * n + 1] = w1;

#pragma unroll
        for (int e = 0; e < 8; e++) s_p[wave][e] = p[e];
        s_zz[wave] = z * z;
        s_t1[wave] = t1;
    }
    __syncthreads();
    if (threadIdx.x < 8) {
        int e = threadIdx.x;
        atomicAdd(&imp[e], s_p[0][e] + s_p[1][e] + s_p[2][e] + s_p[3][e]);
        float cl = 0.f;
#pragma unroll
        for (int w = 0; w < 4; w++) cl += (s_t1[w] == e) ? 1.f : 0.f;
        if (cl > 0.f) atomicAdd(&loadc[e], cl);
    } else if (threadIdx.x == 8) {
        atomicAdd(zsq, s_zz[0] + s_zz[1] + s_zz[2] + s_zz[3]);
    }
}

__global__ void moe_offsets_kernel(const int* __restrict__ count, int* __restrict__ offsets)
{
    int o = 0;
    for (int e = 0; e < E_NUM; e++) { offsets[e] = o; o += count[e]; }
}

// ---------------- shared expert gate+up (bf16 MFMA, fused silu*up) ----------------
__global__ void __launch_bounds__(256, 2)
gemm_sh_gateup(const ushort* __restrict__ Xb, const ushort* __restrict__ Wg,
               const ushort* __restrict__ Wu, ushort* __restrict__ Hsh)
{
    __shared__ ushort As[128 * 32], Bg[128 * 32], Bu[128 * 32];
    const int t = threadIdx.x;
    const int w = t >> 6, lane = t & 63;
    const int m0 = blockIdx.y * 128, f0 = blockIdx.x * 128;

    const int sr = lane >> 2, sc = (lane & 3) * 8;
    const int r0 = (2 * w) * 16 + sr, r1 = r0 + 16;
    const ushort* pa0 = Xb + (size_t)(m0 + r0) * H_DIM + sc;
    const ushort* pa1 = Xb + (size_t)(m0 + r1) * H_DIM + sc;
    const ushort* pg0 = Wg + (size_t)(f0 + r0) * H_DIM + sc;
    const ushort* pg1 = Wg + (size_t)(f0 + r1) * H_DIM + sc;
    const ushort* pu0 = Wu + (size_t)(f0 + r0) * H_DIM + sc;
    const ushort* pu1 = Wu + (size_t)(f0 + r1) * H_DIM + sc;
    ushort* lA0 = &As[(2 * w) * 512]; ushort* lA1 = lA0 + 512;
    ushort* lG0 = &Bg[(2 * w) * 512]; ushort* lG1 = lG0 + 512;
    ushort* lU0 = &Bu[(2 * w) * 512]; ushort* lU1 = lU0 + 512;

    const int wm = w & 1, wn = w >> 1;
    const int lm = lane & 15, quad = lane >> 4;
    const int aoff = (wm * 64 + lm) * 32 + quad * 8;
    const int boff = (wn * 64 + lm) * 32 + quad * 8;

    f32x4 zero4 = {0.f, 0.f, 0.f, 0.f};
    f32x4 accg[4][4], accu[4][4];
#pragma unroll
    for (int i = 0; i < 4; i++)
#pragma unroll
        for (int j = 0; j < 4; j++) { accg[i][j] = zero4; accu[i][j] = zero4; }

    for (int k0 = 0; k0 < H_DIM; k0 += 32) {
        gload16(pa0 + k0, lA0); gload16(pa1 + k0, lA1);
        gload16(pg0 + k0, lG0); gload16(pg1 + k0, lG1);
        gload16(pu0 + k0, lU0); gload16(pu1 + k0, lU1);
        __syncthreads();
        bf16x8 bgf[4], buf_[4];
#pragma unroll
        for (int j = 0; j < 4; j++) {
            bgf[j]  = *(const bf16x8*)&Bg[boff + j * 16 * 32];
            buf_[j] = *(const bf16x8*)&Bu[boff + j * 16 * 32];
        }
#pragma unroll
        for (int i = 0; i < 4; i++) {
            bf16x8 a = *(const bf16x8*)&As[aoff + i * 16 * 32];
#pragma unroll
            for (int j = 0; j < 4; j++) {
                accg[i][j] = MFMA16(a, bgf[j], accg[i][j]);
                accu[i][j] = MFMA16(a, buf_[j], accu[i][j]);
            }
        }
        __syncthreads();
    }
#pragma unroll
    for (int i = 0; i < 4; i++)
#pragma unroll
        for (int j = 0; j < 4; j++) {
            int rb = wm * 64 + i * 16 + quad * 4;
            int col = f0 + wn * 64 + j * 16 + lm;
#pragma unroll
            for (int r = 0; r < 4; r++) {
                float g = accg[i][j][r], u = accu[i][j][r];
                float hv = g / (1.f + __expf(-g)) * u;
                Hsh[(size_t)(m0 + rb + r) * F_DIM + col] = (ushort)f2bf(hv);
            }
        }
}

// ---------------- routed experts gate+up (gathered A rows) ----------------
__global__ void __launch_bounds__(256, 2)
gemm_ex_gateup(const ushort* __restrict__ Xb, const ushort* __restrict__ Weg,
               const ushort* __restrict__ Weu, const int* __restrict__ count,
               const int* __restrict__ offsets, const int* __restrict__ bucket_tok,
               ushort* __restrict__ He, int N)
{
    const int e = blockIdx.z;
    const int cnt = count[e];
    const int m0 = blockIdx.y * 128;
    if (m0 >= cnt) return;
    const int f0 = blockIdx.x * 128;
    const int base = offsets[e];
    const ushort* Wg = Weg + (size_t)e * F_DIM * H_DIM;
    const ushort* Wu = Weu + (size_t)e * F_DIM * H_DIM;

    __shared__ int rows[128];
    __shared__ ushort As[128 * 32], Bg[128 * 32], Bu[128 * 32];
    const int t = threadIdx.x;
    if (t < 128) {
        int r = m0 + t;
        rows[t] = bucket_tok[(size_t)e * N + (r < cnt ? r : cnt - 1)];
    }
    __syncthreads();

    const int w = t >> 6, lane = t & 63;
    const int sr = lane >> 2, sc = (lane & 3) * 8;
    const int r0 = (2 * w) * 16 + sr, r1 = r0 + 16;
    const ushort* pa0 = Xb + (size_t)rows[r0] * H_DIM + sc;
    const ushort* pa1 = Xb + (size_t)rows[r1] * H_DIM + sc;
    const ushort* pg0 = Wg + (size_t)(f0 + r0) * H_DIM + sc;
    const ushort* pg1 = Wg + (size_t)(f0 + r1) * H_DIM + sc;
    const ushort* pu0 = Wu + (size_t)(f0 + r0) * H_DIM + sc;
    const ushort* pu1 = Wu + (size_t)(f0 + r1) * H_DIM + sc;
    ushort* lA0 = &As[(2 * w) * 512]; ushort* lA1 = lA0 + 512;
    ushort* lG0 = &Bg[(2 * w) * 512]; ushort* lG1 = lG0 + 512;
    ushort* lU0 = &Bu[(2 * w) * 512]; ushort* lU1 = lU0 + 512;

    const int wm = w & 1, wn = w >> 1;
    const int lm = lane & 15, quad = lane >> 4;
    const int aoff = (wm * 64 + lm) * 32 + quad * 8;
    const int boff = (wn * 64 + lm) * 32 + quad * 8;

    f32x4 zero4 = {0.f, 0.f, 0.f, 0.f};
    f32x4 accg[4][4], accu[4][4];
#pragma unroll
    for (int i = 0; i < 4; i++)
#pragma unroll
        for (int j = 0; j < 4; j++) { accg[i][j] = zero4; accu[i][j] = zero4; }

    for (int k0 = 0; k0 < H_DIM; k0 += 32) {
        gload16(pa0 + k0, lA0); gload16(pa1 + k0, lA1);
        gload16(pg0 + k0, lG0); gload16(pg1 + k0, lG1);
        gload16(pu0 + k0, lU0); gload16(pu1 + k0, lU1);
        __syncthreads();
        bf16x8 bgf[4], buf_[4];
#pragma unroll
        for (int j = 0; j < 4; j++) {
            bgf[j]  = *(const bf16x8*)&Bg[boff + j * 16 * 32];
            buf_[j] = *(const bf16x8*)&Bu[boff + j * 16 * 32];
        }
#pragma unroll
        for (int i = 0; i < 4; i++) {
            bf16x8 a = *(const bf16x8*)&As[aoff + i * 16 * 32];
#pragma unroll
            for (int j = 0; j < 4; j++) {
                accg[i][j] = MFMA16(a, bgf[j], accg[i][j]);
                accu[i][j] = MFMA16(a, buf_[j], accu[i][j]);
            }
        }
        __syncthreads();
    }
#pragma unroll
    for (int i = 0; i < 4; i++)
#pragma unroll
        for (int j = 0; j < 4; j++) {
            int rb = wm * 64 + i * 16 + quad * 4;
            int col = f0 + wn * 64 + j * 16 + lm;
#pragma unroll
            for (int r = 0; r < 4; r++) {
                int rl = rb + r;
                if (m0 + rl < cnt) {
                    float g = accg[i][j][r], u = accu[i][j][r];
                    float hv = g / (1.f + __expf(-g)) * u;
                    He[(size_t)(base + m0 + rl) * F_DIM + col] = (ushort)f2bf(hv);
                }
            }
        }
}

// ---------------- routed experts down proj -> R fp32 ----------------
__global__ void __launch_bounds__(256)
gemm_ex_down(const ushort* __restrict__ He, const ushort* __restrict__ Wed,
             const int* __restrict__ count, const int* __restrict__ offsets,
             float* __restrict__ R)
{
    const int e = blockIdx.z;
    const int cnt = count[e];
    const int m0 = blockIdx.y * 128;
    if (m0 >= cnt) return;
    const int h0 = blockIdx.x * 128;
    const int base = offsets[e];
    const ushort* Wd = Wed + (size_t)e * H_DIM * F_DIM;

    __shared__ ushort As[128 * 32], Bs[128 * 32];
    const int t = threadIdx.x;
    const int w = t >> 6, lane = t & 63;
    const int sr = lane >> 2, sc = (lane & 3) * 8;
    const int r0 = (2 * w) * 16 + sr, r1 = r0 + 16;
    int ar0 = m0 + r0; if (ar0 >= cnt) ar0 = cnt - 1;
    int ar1 = m0 + r1; if (ar1 >= cnt) ar1 = cnt - 1;
    const ushort* pa0 = He + (size_t)(base + ar0) * F_DIM + sc;
    const ushort* pa1 = He + (size_t)(base + ar1) * F_DIM + sc;
    const ushort* pb0 = Wd + (size_t)(h0 + r0) * F_DIM + sc;
    const ushort* pb1 = Wd + (size_t)(h0 + r1) * F_DIM + sc;
    ushort* lA0 = &As[(2 * w) * 512]; ushort* lA1 = lA0 + 512;
    ushort* lB0 = &Bs[(2 * w) * 512]; ushort* lB1 = lB0 + 512;

    const int wm = w & 1, wn = w >> 1;
    const int lm = lane & 15, quad = lane >> 4;
    const int aoff = (wm * 64 + lm) * 32 + quad * 8;
    const int boff = (wn * 64 + lm) * 32 + quad * 8;

    f32x4 zero4 = {0.f, 0.f, 0.f, 0.f};
    f32x4 acc[4][4];
#pragma unroll
    for (int i = 0; i < 4; i++)
#pragma unroll
        for (int j = 0; j < 4; j++) acc[i][j] = zero4;

    for (int k0 = 0; k0 < F_DIM; k0 += 32) {
        gload16(pa0 + k0, lA0); gload16(pa1 + k0, lA1);
        gload16(pb0 + k0, lB0); gload16(pb1 + k0, lB1);
        __syncthreads();
        bf16x8 bf_[4];
#pragma unroll
        for (int j = 0; j < 4; j++) bf_[j] = *(const bf16x8*)&Bs[boff + j * 16 * 32];
#pragma unroll
        for (int i = 0; i < 4; i++) {
            bf16x8 a = *(const bf16x8*)&As[aoff + i * 16 * 32];
#pragma unroll
            for (int j = 0; j < 4; j++) acc[i][j] = MFMA16(a, bf_[j], acc[i][j]);
        }
        __syncthreads();
    }
#pragma unroll
    for (int i = 0; i < 4; i++)
#pragma unroll
        for (int j = 0; j < 4; j++) {
            int rb = wm * 64 + i * 16 + quad * 4;
            int col = h0 + wn * 64 + j * 16 + lm;
#pragma unroll
            for (int r = 0; r < 4; r++) {
                int rl = rb + r;
                if (m0 + rl < cnt)
                    R[(size_t)(base + m0 + rl) * H_DIM + col] = acc[i][j][r];
            }
        }
}

// ---------------- shared down + top-2 combine ----------------
__global__ void __launch_bounds__(256)
gemm_sh_down_combine(const ushort* __restrict__ Hsh, const ushort* __restrict__ Wd,
                     const float* __restrict__ R, const int* __restrict__ idxA,
                     const int* __restrict__ posA, const float* __restrict__ wA,
                     const int* __restrict__ offsets, float* __restrict__ Y)
{
    const int m0 = blockIdx.y * 128;
    const int h0 = blockIdx.x * 128;

    __shared__ ushort As[128 * 32], Bs[128 * 32];
    __shared__ int r0s[128], r1s[128];
    __shared__ float w0s[128], w1s[128];
    const int t = threadIdx.x;
    if (t < 128) {
        int n = m0 + t;
        int e0 = idxA[2 * n], e1 = idxA[2 * n + 1];
        r0s[t] = offsets[e0] + posA[2 * n];
        r1s[t] = offsets[e1] + posA[2 * n + 1];
        w0s[t] = wA[2 * n];
        w1s[t] = wA[2 * n + 1];
    }

    const int w = t >> 6, lane = t & 63;
    const int sr = lane >> 2, sc = (lane & 3) * 8;
    const int r0 = (2 * w) * 16 + sr, r1 = r0 + 16;
    const ushort* pa0 = Hsh + (size_t)(m0 + r0) * F_DIM + sc;
    const ushort* pa1 = Hsh + (size_t)(m0 + r1) * F_DIM + sc;
    const ushort* pb0 = Wd + (size_t)(h0 + r0) * F_DIM + sc;
    const ushort* pb1 = Wd + (size_t)(h0 + r1) * F_DIM + sc;
    ushort* lA0 = &As[(2 * w) * 512]; ushort* lA1 = lA0 + 512;
    ushort* lB0 = &Bs[(2 * w) * 512]; ushort* lB1 = lB0 + 512;

    const int wm = w & 1, wn = w >> 1;
    const int lm = lane & 15, quad = lane >> 4;
    const int aoff = (wm * 64 + lm) * 32 + quad * 8;
    const int boff = (wn * 64 + lm) * 32 + quad * 8;

    f32x4 zero4 = {0.f, 0.f, 0.f, 0.f};
    f32x4 acc[4][4];
#pragma unroll
    for (int i = 0; i < 4; i++)
#pragma unroll
        for (int j = 0; j < 4; j++) acc[i][j] = zero4;

    for (int k0 = 0; k0 < F_DIM; k0 += 32) {
        gload16(pa0 + k0, lA0); gload16(pa1 + k0, lA1);
        gload16(pb0 + k0, lB0); gload16(pb1 + k0, lB1);
        __syncthreads();
        bf16x8 bf_[4];
#pragma unroll
        for (int j = 0; j < 4; j++) bf_[j] = *(const bf16x8*)&Bs[boff + j * 16 * 32];
#pragma unroll
        for (int i = 0; i < 4; i++) {
            bf16x8 a = *(const bf16x8*)&As[aoff + i * 16 * 32];
#pragma unroll
            for (int j = 0; j < 4; j++) acc[i][j] = MFMA16(a, bf_[j], acc[i][j]);
        }
        __syncthreads();
    }
#pragma unroll
    for (int i = 0; i < 4; i++)
#pragma unroll
        for (int j = 0; j < 4; j++) {
            int rb = wm * 64 + i * 16 + quad * 4;
            int col = h0 + wn * 64 + j * 16 + lm;
#pragma unroll
            for (int r = 0; r < 4; r++) {
                int rl = rb + r;
                float v = acc[i][j][r]
                        + w0s[rl] * R[(size_t)r0s[rl] * H_DIM + col]
                        + w1s[rl] * R[(size_t)r1s[rl] * H_DIM + col];
                Y[(size_t)(m0 + rl) * H_DIM + col] = v;
            }
        }
}

// ---------------- aux loss ----------------
__global__ void moe_aux_kernel(const float* __restrict__ imp, const float* __restrict__ loadc,
                               const float* __restrict__ zsq, float* __restrict__ out, int N)
{
    float is = 0.f, ls = 0.f;
    for (int e = 0; e < E_NUM; e++) { is += imp[e]; ls += loadc[e]; }
    float lb = 0.f;
    for (int e = 0; e < E_NUM; e++)
        lb += (imp[e] / (is + EPSV)) * (loadc[e] / (ls + EPSV));
    lb *= (float)E_NUM;
    float z_loss = 0.001f * (zsq[0] / (float)N);
    out[0] = 0.01f * lb + z_loss;
}

extern "C" void kernel_launch(void* const* d_in, const int* in_sizes, int n_in,
                              void* d_out, int out_size, void* d_ws, size_t ws_size,
                              hipStream_t stream)
{
    const float* x         = (const float*)d_in[0];
    const float* w_router  = (const float*)d_in[1];
    const float* w_sh_gate = (const float*)d_in[2];
    const float* w_sh_up   = (const float*)d_in[3];
    const float* w_sh_down = (const float*)d_in[4];
    const float* w_e_gate  = (const float*)d_in[5];
    const float* w_e_up    = (const float*)d_in[6];
    const float* w_e_down  = (const float*)d_in[7];
    float* out = (float*)d_out;
    int N = in_sizes[0] / H_DIM;  // 4096

    char* ws = (char*)d_ws;
    int*   count   = (int*)(ws + 0);
    int*   offsets = (int*)(ws + 32);
    float* imp     = (float*)(ws + 64);
    float* loadc   = (float*)(ws + 96);
    float* zsq     = (float*)(ws + 128);
    size_t off = 256;
    int*   idxA = (int*)(ws + off);  off += (size_t)N * 2 * 4;
    int*   posA = (int*)(ws + off);  off += (size_t)N * 2 * 4;
    float* wA   = (float*)(ws + off); off += (size_t)N * 2 * 4;
    int*   bucket_tok = (int*)(ws + off); off += (size_t)E_NUM * N * 4;
    off = (off + 255) & ~(size_t)255;
    ushort* Xb  = (ushort*)(ws + off); off += (size_t)N * H_DIM * 2;
    ushort* Wsg = (ushort*)(ws + off); off += (size_t)F_DIM * H_DIM * 2;
    ushort* Wsu = (ushort*)(ws + off); off += (size_t)F_DIM * H_DIM * 2;
    ushort* Wsd = (ushort*)(ws + off); off += (size_t)H_DIM * F_DIM * 2;
    ushort* Weg = (ushort*)(ws + off); off += (size_t)E_NUM * F_DIM * H_DIM * 2;
    ushort* Weu = (ushort*)(ws + off); off += (size_t)E_NUM * F_DIM * H_DIM * 2;
    ushort* Wed = (ushort*)(ws + off); off += (size_t)E_NUM * H_DIM * F_DIM * 2;
    ushort* Hsh = (ushort*)(ws + off); off += (size_t)N * F_DIM * 2;
    ushort* He  = (ushort*)(ws + off); off += (size_t)2 * N * F_DIM * 2;
    float*  R   = (float*)(ws + off);  off += (size_t)2 * N * H_DIM * 4;

    hipMemsetAsync(ws, 0, 256, stream);

    // fp32 -> bf16 conversions
    {
        struct { const float* s; ushort* d; size_t n; } cv[7] = {
            { x,         Xb,  (size_t)N * H_DIM },
            { w_sh_gate, Wsg, (size_t)F_DIM * H_DIM },
            { w_sh_up,   Wsu, (size_t)F_DIM * H_DIM },
            { w_sh_down, Wsd, (size_t)H_DIM * F_DIM },
            { w_e_gate,  Weg, (size_t)E_NUM * F_DIM * H_DIM },
            { w_e_up,    Weu, (size_t)E_NUM * F_DIM * H_DIM },
            { w_e_down,  Wed, (size_t)E_NUM * H_DIM * F_DIM },
        };
        for (int i = 0; i < 7; i++) {
            int n8 = (int)(cv[i].n / 8);
            cvt_bf16_kernel<<<(n8 + 255) / 256, 256, 0, stream>>>(cv[i].s, cv[i].d, n8);
        }
    }

    moe_router_kernel<<<N / 4, 256, 0, stream>>>(x, w_router, N, count, imp, loadc, zsq,
                                                 idxA, posA, wA, bucket_tok);
    moe_offsets_kernel<<<1, 1, 0, stream>>>(count, offsets);

    gemm_sh_gateup<<<dim3(F_DIM / 128, N / 128), 256, 0, stream>>>(Xb, Wsg, Wsu, Hsh);
    gemm_ex_gateup<<<dim3(F_DIM / 128, N / 128, E_NUM), 256, 0, stream>>>(
        Xb, Weg, Weu, count, offsets, bucket_tok, He, N);
    gemm_ex_down<<<dim3(H_DIM / 128, N / 128, E_NUM), 256, 0, stream>>>(
        He, Wed, count, offsets, R);
    gemm_sh_down_combine<<<dim3(H_DIM / 128, N / 128), 256, 0, stream>>>(
        Hsh, Wsd, R, idxA, posA, wA, offsets, out);
    moe_aux_kernel<<<1, 1, 0, stream>>>(imp, loadc, zsq, out + (size_t)N * H_DIM, N);
}

// Round 3
// 628.477 us; speedup vs baseline: 5.0142x; 1.0944x over previous
//
#include <hip/hip_runtime.h>
#include <math.h>

// MoE FFN: top-2 of 8 experts + shared expert, H=1024, F=2048, N=4096.
// Round 3: atomic-free routing (logits -> per-expert ballot scan -> reduce).
// R2 post-mortem: router was 127us, all contended-atomic stalls (VALUBusy 3%).
// GEMMs: bf16 MFMA, m97 structure (128x128 tile, 16x16x32, global_load_lds w=16).

#define H_DIM 1024
#define F_DIM 2048
#define E_NUM 8
#define EPSV 1e-9f

typedef __bf16 bf16x8 __attribute__((ext_vector_type(8)));
typedef float f32x4 __attribute__((ext_vector_type(4)));

#define MFMA16(a, b, c) __builtin_amdgcn_mfma_f32_16x16x32_bf16(a, b, c, 0, 0, 0)

__device__ __forceinline__ unsigned f2bf(float f) {
    unsigned u = __float_as_uint(f);
    return (u + 0x7FFFu + ((u >> 16) & 1u)) >> 16;  // RNE
}

// async global->LDS, 16B per lane; lds ptr must be wave-uniform
__device__ __forceinline__ void gload16(const ushort* g, ushort* l) {
    __builtin_amdgcn_global_load_lds(
        (__attribute__((address_space(1))) void*)(void*)const_cast<ushort*>(g),
        (__attribute__((address_space(3))) void*)l, 16, 0, 0);
}

// ---------------- fp32 -> bf16 conversion (8 elems/thread) ----------------
__global__ void cvt_bf16_kernel(const float* __restrict__ src, ushort* __restrict__ dst, int n8) {
    int i = blockIdx.x * 256 + threadIdx.x;
    if (i >= n8) return;
    float4 a = ((const float4*)src)[2 * i];
    float4 b = ((const float4*)src)[2 * i + 1];
    uint4 o;
    o.x = f2bf(a.x) | (f2bf(a.y) << 16);
    o.y = f2bf(a.z) | (f2bf(a.w) << 16);
    o.z = f2bf(b.x) | (f2bf(b.y) << 16);
    o.w = f2bf(b.z) | (f2bf(b.w) << 16);
    ((uint4*)dst)[i] = o;
}

// ---------------- router stage 1: logits/softmax/top-2 (no atomics) --------
__global__ void router_logits_kernel(const float* __restrict__ X,
                                     const float* __restrict__ Wr, int N,
                                     float* __restrict__ P, float* __restrict__ zz,
                                     int* __restrict__ idxA, float* __restrict__ wA)
{
    int wave = threadIdx.x >> 6;
    int lane = threadIdx.x & 63;
    int n = blockIdx.x * 4 + wave;

    float acc[8];
#pragma unroll
    for (int e = 0; e < 8; e++) acc[e] = 0.f;
    const float* xr = X + (size_t)n * H_DIM;
    for (int h = lane; h < H_DIM; h += 64) {
        float xv = xr[h];
#pragma unroll
        for (int e = 0; e < 8; e++) acc[e] += xv * Wr[e * H_DIM + h];
    }
#pragma unroll
    for (int off = 32; off > 0; off >>= 1) {
#pragma unroll
        for (int e = 0; e < 8; e++) acc[e] += __shfl_xor(acc[e], off, 64);
    }

    if (lane == 0) {
        float m = acc[0];
#pragma unroll
        for (int e = 1; e < 8; e++) m = fmaxf(m, acc[e]);
        float p[8];
        float s = 0.f;
#pragma unroll
        for (int e = 0; e < 8; e++) { p[e] = expf(acc[e] - m); s += p[e]; }
        float z = m + logf(s);
        float inv = 1.f / s;
#pragma unroll
        for (int e = 0; e < 8; e++) p[e] *= inv;
        // strict > keeps lowest index on ties (matches lax.top_k)
        int t1 = 0; float b1 = p[0];
#pragma unroll
        for (int e = 1; e < 8; e++) if (p[e] > b1) { b1 = p[e]; t1 = e; }
        int t2 = (t1 == 0) ? 1 : 0; float b2 = p[t2];
#pragma unroll
        for (int e = 0; e < 8; e++) if (e != t1 && p[e] > b2) { b2 = p[e]; t2 = e; }

        float wsum = b1 + b2 + EPSV;
#pragma unroll
        for (int e = 0; e < 8; e++) P[(size_t)n * 8 + e] = p[e];
        zz[n] = z * z;
        idxA[2 * n] = t1; idxA[2 * n + 1] = t2;
        wA[2 * n] = b1 / wsum; wA[2 * n + 1] = b2 / wsum;
    }
}

// ---------------- router stage 2: per-expert bucket scan (8 blocks) --------
// Deterministic token-order positions via ballot prefix-scan. No atomics.
__global__ void bucket_scan_kernel(const int* __restrict__ idxA, int N,
                                   int* __restrict__ count, int* __restrict__ loadc_i,
                                   int* __restrict__ posA, int* __restrict__ bucket_tok)
{
    const int e = blockIdx.x;
    const int t = threadIdx.x;
    const int wave = t >> 6, lane = t & 63;
    __shared__ int wsum[4], wbase[4];
    __shared__ int s_run;
    __shared__ int s_load[4];
    if (t == 0) s_run = 0;
    int load1 = 0;

    for (int c0 = 0; c0 < 2 * N; c0 += 256) {
        int i = c0 + t;
        int v = idxA[i];
        bool pred = (v == e);
        if (pred && ((i & 1) == 0)) load1++;
        unsigned long long mask = __ballot(pred);
        int prefix = __popcll(mask & ((1ull << lane) - 1ull));
        if (lane == 0) wsum[wave] = __popcll(mask);
        __syncthreads();
        if (t == 0) {
            int b = s_run;
            for (int w2 = 0; w2 < 4; w2++) { wbase[w2] = b; b += wsum[w2]; }
            s_run = b;
        }
        __syncthreads();
        if (pred) {
            int pos = wbase[wave] + prefix;
            posA[i] = pos;
            bucket_tok[(size_t)e * N + pos] = i >> 1;
        }
    }
    // reduce load1 (top-1 count) across block
#pragma unroll
    for (int off = 32; off > 0; off >>= 1) load1 += __shfl_down(load1, off, 64);
    if (lane == 0) s_load[wave] = load1;
    __syncthreads();
    if (t == 0) {
        count[e] = s_run;
        loadc_i[e] = s_load[0] + s_load[1] + s_load[2] + s_load[3];
    }
}

__global__ void moe_offsets_kernel(const int* __restrict__ count, int* __restrict__ offsets)
{
    int o = 0;
    for (int e = 0; e < E_NUM; e++) { offsets[e] = o; o += count[e]; }
}

// ---------------- router stage 3: aux-loss reduction (1 block) -------------
__global__ void aux_reduce_kernel(const float* __restrict__ P, const float* __restrict__ zz,
                                  const int* __restrict__ loadc_i, int N,
                                  float* __restrict__ aux_out)
{
    __shared__ float s_imp[256];
    __shared__ float s_z[256];
    const int t = threadIdx.x;
    const int e = t & 7, c = t >> 3;
    float si = 0.f;
    for (int n = c; n < N; n += 32) si += P[(size_t)n * 8 + e];
    s_imp[t] = si;
    float sz = 0.f;
    for (int n = t; n < N; n += 256) sz += zz[n];
    s_z[t] = sz;
    __syncthreads();
    if (t < 8) {
        float tot = 0.f;
        for (int c2 = 0; c2 < 32; c2++) tot += s_imp[c2 * 8 + t];
        s_imp[t] = tot;
    }
    if (t == 8) {
        float z = 0.f;
        for (int i = 0; i < 256; i++) z += s_z[i];
        s_z[0] = z;
    }
    __syncthreads();
    if (t == 0) {
        float is = 0.f, ls = 0.f, impv[8], ldv[8];
        for (int e2 = 0; e2 < 8; e2++) {
            impv[e2] = s_imp[e2];
            ldv[e2] = (float)loadc_i[e2];
            is += impv[e2]; ls += ldv[e2];
        }
        float lb = 0.f;
        for (int e2 = 0; e2 < 8; e2++)
            lb += (impv[e2] / (is + EPSV)) * (ldv[e2] / (ls + EPSV));
        lb *= (float)E_NUM;
        float zl = 0.001f * (s_z[0] / (float)N);
        aux_out[0] = 0.01f * lb + zl;
    }
}

// ---------------- shared expert gate+up (bf16 MFMA, fused silu*up) ----------------
__global__ void __launch_bounds__(256, 2)
gemm_sh_gateup(const ushort* __restrict__ Xb, const ushort* __restrict__ Wg,
               const ushort* __restrict__ Wu, ushort* __restrict__ Hsh)
{
    __shared__ ushort As[128 * 32], Bg[128 * 32], Bu[128 * 32];
    const int t = threadIdx.x;
    const int w = t >> 6, lane = t & 63;
    const int m0 = blockIdx.y * 128, f0 = blockIdx.x * 128;

    const int sr = lane >> 2, sc = (lane & 3) * 8;
    const int r0 = (2 * w) * 16 + sr, r1 = r0 + 16;
    const ushort* pa0 = Xb + (size_t)(m0 + r0) * H_DIM + sc;
    const ushort* pa1 = Xb + (size_t)(m0 + r1) * H_DIM + sc;
    const ushort* pg0 = Wg + (size_t)(f0 + r0) * H_DIM + sc;
    const ushort* pg1 = Wg + (size_t)(f0 + r1) * H_DIM + sc;
    const ushort* pu0 = Wu + (size_t)(f0 + r0) * H_DIM + sc;
    const ushort* pu1 = Wu + (size_t)(f0 + r1) * H_DIM + sc;
    ushort* lA0 = &As[(2 * w) * 512]; ushort* lA1 = lA0 + 512;
    ushort* lG0 = &Bg[(2 * w) * 512]; ushort* lG1 = lG0 + 512;
    ushort* lU0 = &Bu[(2 * w) * 512]; ushort* lU1 = lU0 + 512;

    const int wm = w & 1, wn = w >> 1;
    const int lm = lane & 15, quad = lane >> 4;
    const int aoff = (wm * 64 + lm) * 32 + quad * 8;
    const int boff = (wn * 64 + lm) * 32 + quad * 8;

    f32x4 zero4 = {0.f, 0.f, 0.f, 0.f};
    f32x4 accg[4][4], accu[4][4];
#pragma unroll
    for (int i = 0; i < 4; i++)
#pragma unroll
        for (int j = 0; j < 4; j++) { accg[i][j] = zero4; accu[i][j] = zero4; }

    for (int k0 = 0; k0 < H_DIM; k0 += 32) {
        gload16(pa0 + k0, lA0); gload16(pa1 + k0, lA1);
        gload16(pg0 + k0, lG0); gload16(pg1 + k0, lG1);
        gload16(pu0 + k0, lU0); gload16(pu1 + k0, lU1);
        __syncthreads();
        bf16x8 bgf[4], buf_[4];
#pragma unroll
        for (int j = 0; j < 4; j++) {
            bgf[j]  = *(const bf16x8*)&Bg[boff + j * 16 * 32];
            buf_[j] = *(const bf16x8*)&Bu[boff + j * 16 * 32];
        }
#pragma unroll
        for (int i = 0; i < 4; i++) {
            bf16x8 a = *(const bf16x8*)&As[aoff + i * 16 * 32];
#pragma unroll
            for (int j = 0; j < 4; j++) {
                accg[i][j] = MFMA16(a, bgf[j], accg[i][j]);
                accu[i][j] = MFMA16(a, buf_[j], accu[i][j]);
            }
        }
        __syncthreads();
    }
#pragma unroll
    for (int i = 0; i < 4; i++)
#pragma unroll
        for (int j = 0; j < 4; j++) {
            int rb = wm * 64 + i * 16 + quad * 4;
            int col = f0 + wn * 64 + j * 16 + lm;
#pragma unroll
            for (int r = 0; r < 4; r++) {
                float g = accg[i][j][r], u = accu[i][j][r];
                float hv = g / (1.f + __expf(-g)) * u;
                Hsh[(size_t)(m0 + rb + r) * F_DIM + col] = (ushort)f2bf(hv);
            }
        }
}

// ---------------- routed experts gate+up (gathered A rows) ----------------
__global__ void __launch_bounds__(256, 2)
gemm_ex_gateup(const ushort* __restrict__ Xb, const ushort* __restrict__ Weg,
               const ushort* __restrict__ Weu, const int* __restrict__ count,
               const int* __restrict__ offsets, const int* __restrict__ bucket_tok,
               ushort* __restrict__ He, int N)
{
    const int e = blockIdx.z;
    const int cnt = count[e];
    const int m0 = blockIdx.y * 128;
    if (m0 >= cnt) return;
    const int f0 = blockIdx.x * 128;
    const int base = offsets[e];
    const ushort* Wg = Weg + (size_t)e * F_DIM * H_DIM;
    const ushort* Wu = Weu + (size_t)e * F_DIM * H_DIM;

    __shared__ int rows[128];
    __shared__ ushort As[128 * 32], Bg[128 * 32], Bu[128 * 32];
    const int t = threadIdx.x;
    if (t < 128) {
        int r = m0 + t;
        rows[t] = bucket_tok[(size_t)e * N + (r < cnt ? r : cnt - 1)];
    }
    __syncthreads();

    const int w = t >> 6, lane = t & 63;
    const int sr = lane >> 2, sc = (lane & 3) * 8;
    const int r0 = (2 * w) * 16 + sr, r1 = r0 + 16;
    const ushort* pa0 = Xb + (size_t)rows[r0] * H_DIM + sc;
    const ushort* pa1 = Xb + (size_t)rows[r1] * H_DIM + sc;
    const ushort* pg0 = Wg + (size_t)(f0 + r0) * H_DIM + sc;
    const ushort* pg1 = Wg + (size_t)(f0 + r1) * H_DIM + sc;
    const ushort* pu0 = Wu + (size_t)(f0 + r0) * H_DIM + sc;
    const ushort* pu1 = Wu + (size_t)(f0 + r1) * H_DIM + sc;
    ushort* lA0 = &As[(2 * w) * 512]; ushort* lA1 = lA0 + 512;
    ushort* lG0 = &Bg[(2 * w) * 512]; ushort* lG1 = lG0 + 512;
    ushort* lU0 = &Bu[(2 * w) * 512]; ushort* lU1 = lU0 + 512;

    const int wm = w & 1, wn = w >> 1;
    const int lm = lane & 15, quad = lane >> 4;
    const int aoff = (wm * 64 + lm) * 32 + quad * 8;
    const int boff = (wn * 64 + lm) * 32 + quad * 8;

    f32x4 zero4 = {0.f, 0.f, 0.f, 0.f};
    f32x4 accg[4][4], accu[4][4];
#pragma unroll
    for (int i = 0; i < 4; i++)
#pragma unroll
        for (int j = 0; j < 4; j++) { accg[i][j] = zero4; accu[i][j] = zero4; }

    for (int k0 = 0; k0 < H_DIM; k0 += 32) {
        gload16(pa0 + k0, lA0); gload16(pa1 + k0, lA1);
        gload16(pg0 + k0, lG0); gload16(pg1 + k0, lG1);
        gload16(pu0 + k0, lU0); gload16(pu1 + k0, lU1);
        __syncthreads();
        bf16x8 bgf[4], buf_[4];
#pragma unroll
        for (int j = 0; j < 4; j++) {
            bgf[j]  = *(const bf16x8*)&Bg[boff + j * 16 * 32];
            buf_[j] = *(const bf16x8*)&Bu[boff + j * 16 * 32];
        }
#pragma unroll
        for (int i = 0; i < 4; i++) {
            bf16x8 a = *(const bf16x8*)&As[aoff + i * 16 * 32];
#pragma unroll
            for (int j = 0; j < 4; j++) {
                accg[i][j] = MFMA16(a, bgf[j], accg[i][j]);
                accu[i][j] = MFMA16(a, buf_[j], accu[i][j]);
            }
        }
        __syncthreads();
    }
#pragma unroll
    for (int i = 0; i < 4; i++)
#pragma unroll
        for (int j = 0; j < 4; j++) {
            int rb = wm * 64 + i * 16 + quad * 4;
            int col = f0 + wn * 64 + j * 16 + lm;
#pragma unroll
            for (int r = 0; r < 4; r++) {
                int rl = rb + r;
                if (m0 + rl < cnt) {
                    float g = accg[i][j][r], u = accu[i][j][r];
                    float hv = g / (1.f + __expf(-g)) * u;
                    He[(size_t)(base + m0 + rl) * F_DIM + col] = (ushort)f2bf(hv);
                }
            }
        }
}

// ---------------- routed experts down proj -> R fp32 ----------------
__global__ void __launch_bounds__(256)
gemm_ex_down(const ushort* __restrict__ He, const ushort* __restrict__ Wed,
             const int* __restrict__ count, const int* __restrict__ offsets,
             float* __restrict__ R)
{
    const int e = blockIdx.z;
    const int cnt = count[e];
    const int m0 = blockIdx.y * 128;
    if (m0 >= cnt) return;
    const int h0 = blockIdx.x * 128;
    const int base = offsets[e];
    const ushort* Wd = Wed + (size_t)e * H_DIM * F_DIM;

    __shared__ ushort As[128 * 32], Bs[128 * 32];
    const int t = threadIdx.x;
    const int w = t >> 6, lane = t & 63;
    const int sr = lane >> 2, sc = (lane & 3) * 8;
    const int r0 = (2 * w) * 16 + sr, r1 = r0 + 16;
    int ar0 = m0 + r0; if (ar0 >= cnt) ar0 = cnt - 1;
    int ar1 = m0 + r1; if (ar1 >= cnt) ar1 = cnt - 1;
    const ushort* pa0 = He + (size_t)(base + ar0) * F_DIM + sc;
    const ushort* pa1 = He + (size_t)(base + ar1) * F_DIM + sc;
    const ushort* pb0 = Wd + (size_t)(h0 + r0) * F_DIM + sc;
    const ushort* pb1 = Wd + (size_t)(h0 + r1) * F_DIM + sc;
    ushort* lA0 = &As[(2 * w) * 512]; ushort* lA1 = lA0 + 512;
    ushort* lB0 = &Bs[(2 * w) * 512]; ushort* lB1 = lB0 + 512;

    const int wm = w & 1, wn = w >> 1;
    const int lm = lane & 15, quad = lane >> 4;
    const int aoff = (wm * 64 + lm) * 32 + quad * 8;
    const int boff = (wn * 64 + lm) * 32 + quad * 8;

    f32x4 zero4 = {0.f, 0.f, 0.f, 0.f};
    f32x4 acc[4][4];
#pragma unroll
    for (int i = 0; i < 4; i++)
#pragma unroll
        for (int j = 0; j < 4; j++) acc[i][j] = zero4;

    for (int k0 = 0; k0 < F_DIM; k0 += 32) {
        gload16(pa0 + k0, lA0); gload16(pa1 + k0, lA1);
        gload16(pb0 + k0, lB0); gload16(pb1 + k0, lB1);
        __syncthreads();
        bf16x8 bf_[4];
#pragma unroll
        for (int j = 0; j < 4; j++) bf_[j] = *(const bf16x8*)&Bs[boff + j * 16 * 32];
#pragma unroll
        for (int i = 0; i < 4; i++) {
            bf16x8 a = *(const bf16x8*)&As[aoff + i * 16 * 32];
#pragma unroll
            for (int j = 0; j < 4; j++) acc[i][j] = MFMA16(a, bf_[j], acc[i][j]);
        }
        __syncthreads();
    }
#pragma unroll
    for (int i = 0; i < 4; i++)
#pragma unroll
        for (int j = 0; j < 4; j++) {
            int rb = wm * 64 + i * 16 + quad * 4;
            int col = h0 + wn * 64 + j * 16 + lm;
#pragma unroll
            for (int r = 0; r < 4; r++) {
                int rl = rb + r;
                if (m0 + rl < cnt)
                    R[(size_t)(base + m0 + rl) * H_DIM + col] = acc[i][j][r];
            }
        }
}

// ---------------- shared down + top-2 combine ----------------
__global__ void __launch_bounds__(256)
gemm_sh_down_combine(const ushort* __restrict__ Hsh, const ushort* __restrict__ Wd,
                     const float* __restrict__ R, const int* __restrict__ idxA,
                     const int* __restrict__ posA, const float* __restrict__ wA,
                     const int* __restrict__ offsets, float* __restrict__ Y)
{
    const int m0 = blockIdx.y * 128;
    const int h0 = blockIdx.x * 128;

    __shared__ ushort As[128 * 32], Bs[128 * 32];
    __shared__ int r0s[128], r1s[128];
    __shared__ float w0s[128], w1s[128];
    const int t = threadIdx.x;
    if (t < 128) {
        int n = m0 + t;
        int e0 = idxA[2 * n], e1 = idxA[2 * n + 1];
        r0s[t] = offsets[e0] + posA[2 * n];
        r1s[t] = offsets[e1] + posA[2 * n + 1];
        w0s[t] = wA[2 * n];
        w1s[t] = wA[2 * n + 1];
    }

    const int w = t >> 6, lane = t & 63;
    const int sr = lane >> 2, sc = (lane & 3) * 8;
    const int r0 = (2 * w) * 16 + sr, r1 = r0 + 16;
    const ushort* pa0 = Hsh + (size_t)(m0 + r0) * F_DIM + sc;
    const ushort* pa1 = Hsh + (size_t)(m0 + r1) * F_DIM + sc;
    const ushort* pb0 = Wd + (size_t)(h0 + r0) * F_DIM + sc;
    const ushort* pb1 = Wd + (size_t)(h0 + r1) * F_DIM + sc;
    ushort* lA0 = &As[(2 * w) * 512]; ushort* lA1 = lA0 + 512;
    ushort* lB0 = &Bs[(2 * w) * 512]; ushort* lB1 = lB0 + 512;

    const int wm = w & 1, wn = w >> 1;
    const int lm = lane & 15, quad = lane >> 4;
    const int aoff = (wm * 64 + lm) * 32 + quad * 8;
    const int boff = (wn * 64 + lm) * 32 + quad * 8;

    f32x4 zero4 = {0.f, 0.f, 0.f, 0.f};
    f32x4 acc[4][4];
#pragma unroll
    for (int i = 0; i < 4; i++)
#pragma unroll
        for (int j = 0; j < 4; j++) acc[i][j] = zero4;

    for (int k0 = 0; k0 < F_DIM; k0 += 32) {
        gload16(pa0 + k0, lA0); gload16(pa1 + k0, lA1);
        gload16(pb0 + k0, lB0); gload16(pb1 + k0, lB1);
        __syncthreads();
        bf16x8 bf_[4];
#pragma unroll
        for (int j = 0; j < 4; j++) bf_[j] = *(const bf16x8*)&Bs[boff + j * 16 * 32];
#pragma unroll
        for (int i = 0; i < 4; i++) {
            bf16x8 a = *(const bf16x8*)&As[aoff + i * 16 * 32];
#pragma unroll
            for (int j = 0; j < 4; j++) acc[i][j] = MFMA16(a, bf_[j], acc[i][j]);
        }
        __syncthreads();
    }
#pragma unroll
    for (int i = 0; i < 4; i++)
#pragma unroll
        for (int j = 0; j < 4; j++) {
            int rb = wm * 64 + i * 16 + quad * 4;
            int col = h0 + wn * 64 + j * 16 + lm;
#pragma unroll
            for (int r = 0; r < 4; r++) {
                int rl = rb + r;
                float v = acc[i][j][r]
                        + w0s[rl] * R[(size_t)r0s[rl] * H_DIM + col]
                        + w1s[rl] * R[(size_t)r1s[rl] * H_DIM + col];
                Y[(size_t)(m0 + rl) * H_DIM + col] = v;
            }
        }
}

extern "C" void kernel_launch(void* const* d_in, const int* in_sizes, int n_in,
                              void* d_out, int out_size, void* d_ws, size_t ws_size,
                              hipStream_t stream)
{
    const float* x         = (const float*)d_in[0];
    const float* w_router  = (const float*)d_in[1];
    const float* w_sh_gate = (const float*)d_in[2];
    const float* w_sh_up   = (const float*)d_in[3];
    const float* w_sh_down = (const float*)d_in[4];
    const float* w_e_gate  = (const float*)d_in[5];
    const float* w_e_up    = (const float*)d_in[6];
    const float* w_e_down  = (const float*)d_in[7];
    float* out = (float*)d_out;
    int N = in_sizes[0] / H_DIM;  // 4096

    char* ws = (char*)d_ws;
    int*   count   = (int*)(ws + 0);
    int*   offsets = (int*)(ws + 32);
    int*   loadc_i = (int*)(ws + 64);
    size_t off = 256;
    int*   idxA = (int*)(ws + off);  off += (size_t)N * 2 * 4;
    int*   posA = (int*)(ws + off);  off += (size_t)N * 2 * 4;
    float* wA   = (float*)(ws + off); off += (size_t)N * 2 * 4;
    int*   bucket_tok = (int*)(ws + off); off += (size_t)E_NUM * N * 4;
    float* P    = (float*)(ws + off); off += (size_t)N * 8 * 4;
    float* zz   = (float*)(ws + off); off += (size_t)N * 4;
    off = (off + 255) & ~(size_t)255;
    ushort* Xb  = (ushort*)(ws + off); off += (size_t)N * H_DIM * 2;
    ushort* Wsg = (ushort*)(ws + off); off += (size_t)F_DIM * H_DIM * 2;
    ushort* Wsu = (ushort*)(ws + off); off += (size_t)F_DIM * H_DIM * 2;
    ushort* Wsd = (ushort*)(ws + off); off += (size_t)H_DIM * F_DIM * 2;
    ushort* Weg = (ushort*)(ws + off); off += (size_t)E_NUM * F_DIM * H_DIM * 2;
    ushort* Weu = (ushort*)(ws + off); off += (size_t)E_NUM * F_DIM * H_DIM * 2;
    ushort* Wed = (ushort*)(ws + off); off += (size_t)E_NUM * H_DIM * F_DIM * 2;
    ushort* Hsh = (ushort*)(ws + off); off += (size_t)N * F_DIM * 2;
    ushort* He  = (ushort*)(ws + off); off += (size_t)2 * N * F_DIM * 2;
    float*  R   = (float*)(ws + off);  off += (size_t)2 * N * H_DIM * 4;

    // fp32 -> bf16 conversions
    {
        struct { const float* s; ushort* d; size_t n; } cv[7] = {
            { x,         Xb,  (size_t)N * H_DIM },
            { w_sh_gate, Wsg, (size_t)F_DIM * H_DIM },
            { w_sh_up,   Wsu, (size_t)F_DIM * H_DIM },
            { w_sh_down, Wsd, (size_t)H_DIM * F_DIM },
            { w_e_gate,  Weg, (size_t)E_NUM * F_DIM * H_DIM },
            { w_e_up,    Weu, (size_t)E_NUM * F_DIM * H_DIM },
            { w_e_down,  Wed, (size_t)E_NUM * H_DIM * F_DIM },
        };
        for (int i = 0; i < 7; i++) {
            int n8 = (int)(cv[i].n / 8);
            cvt_bf16_kernel<<<(n8 + 255) / 256, 256, 0, stream>>>(cv[i].s, cv[i].d, n8);
        }
    }

    router_logits_kernel<<<N / 4, 256, 0, stream>>>(x, w_router, N, P, zz, idxA, wA);
    bucket_scan_kernel<<<E_NUM, 256, 0, stream>>>(idxA, N, count, loadc_i, posA, bucket_tok);
    moe_offsets_kernel<<<1, 1, 0, stream>>>(count, offsets);
    aux_reduce_kernel<<<1, 256, 0, stream>>>(P, zz, loadc_i, N, out + (size_t)N * H_DIM);

    gemm_sh_gateup<<<dim3(F_DIM / 128, N / 128), 256, 0, stream>>>(Xb, Wsg, Wsu, Hsh);
    gemm_ex_gateup<<<dim3(F_DIM / 128, N / 128, E_NUM), 256, 0, stream>>>(
        Xb, Weg, Weu, count, offsets, bucket_tok, He, N);
    gemm_ex_down<<<dim3(H_DIM / 128, N / 128, E_NUM), 256, 0, stream>>>(
        He, Wed, count, offsets, R);
    gemm_sh_down_combine<<<dim3(H_DIM / 128, N / 128), 256, 0, stream>>>(
        Hsh, Wsd, R, idxA, posA, wA, offsets, out);
}